// Round 7
// baseline (255.784 us; speedup 1.0000x reference)
//
#include <hip/hip_runtime.h>
#include <math.h>

#define HEADS 8
#define DK 32
#define B_ 4
#define C_ 256
#define NVOX 1728   // 12*12*12
#define DE 64       // effective head dim: Q'=[q;pos], K'=[k;q]
#define PITCH 72    // attn P-buffer pitch (shorts): 144 B rows
#define XPITCH 136  // fproj x-chunk LDS pitch (shorts)
#define CPITCH 36   // fproj cbuf pitch (floats)
#define LOG2E 1.44269504088896f

typedef short bf16x8 __attribute__((ext_vector_type(8)));
typedef float f32x16 __attribute__((ext_vector_type(16)));

__device__ inline short f2bf(float x) {
    unsigned u = __float_as_uint(x);
    unsigned r = u + 0x7fffu + ((u >> 16) & 1u);
    return (short)(r >> 16);
}
__device__ inline float bf2f(short h) {
    return __uint_as_float(((unsigned)(unsigned short)h) << 16);
}
__device__ inline f32x16 mfma32(bf16x8 a, bf16x8 b, f32x16 c) {
    return __builtin_amdgcn_mfma_f32_32x32x16_bf16(a, b, c, 0, 0, 0);
}

// ---------------------------------------------------------------------------
// Weight hi/lo split (layout [mat][o][c])
// ---------------------------------------------------------------------------
__global__ void wsplit_kernel(const float* __restrict__ wq,
                              const float* __restrict__ wk,
                              const float* __restrict__ wv,
                              short* __restrict__ whi, short* __restrict__ wlo) {
    int idx = blockIdx.x * 256 + threadIdx.x;   // 3*65536
    int m = idx >> 16;
    const float* w = (m == 0) ? wq : (m == 1) ? wk : wv;
    float v = w[idx & 65535];
    short h = f2bf(v);
    whi[idx] = h;
    wlo[idx] = f2bf(v - bf2f(h));
}

// ---------------------------------------------------------------------------
// x transpose + hi/lo split:  x[b][c][n] fp32 -> xbhi/xblo [b][n][c] bf16
// ---------------------------------------------------------------------------
__global__ __launch_bounds__(256)
void xsplit_kernel(const float* __restrict__ x,
                   short* __restrict__ xbhi, short* __restrict__ xblo) {
    __shared__ float tile[64][65];
    int nb = blockIdx.x * 64, c0 = blockIdx.y * 64, b = blockIdx.z;
    int t = threadIdx.x;
    const float* xb = x + (size_t)b * C_ * NVOX;
    for (int e = t; e < 4096; e += 256) {
        int ci = e >> 6, nl = e & 63;
        tile[ci][nl] = xb[(size_t)(c0 + ci) * NVOX + nb + nl];
    }
    __syncthreads();
    for (int e = t; e < 512; e += 256) {
        int n = e >> 3, cg = (e & 7) * 8;
        union { short s[8]; uint4 v; } hi, lo;
        #pragma unroll
        for (int j = 0; j < 8; j++) {
            float v = tile[cg + j][n];
            short h = f2bf(v);
            hi.s[j] = h;
            lo.s[j] = f2bf(v - bf2f(h));
        }
        size_t off = ((size_t)b * NVOX + nb + n) * C_ + c0 + cg;
        *(uint4*)&xbhi[off] = hi.v;
        *(uint4*)&xblo[off] = lo.v;
    }
}

// ---------------------------------------------------------------------------
// pos -> Q' upper half [32:64), bf16 hi/lo.
// ---------------------------------------------------------------------------
__global__ void pos_kernel(const float* __restrict__ rel_d,
                           const float* __restrict__ rel_h,
                           const float* __restrict__ rel_w,
                           short* __restrict__ QhiT, short* __restrict__ QloT) {
    int t = threadIdx.x;
    int nl = t & 63, dd0 = (t >> 6) * 8;
    int n = blockIdx.x * 64 + nl;
    int h = blockIdx.y, b = blockIdx.z;
    int bh = b * HEADS + h;
    int di = n / 144, wi = (n / 12) % 12, hi = n % 12;
    union { short s[8]; uint4 v; } ph, pl;
    #pragma unroll
    for (int o = 0; o < 8; o++) {
        int hd = h * DK + dd0 + o;
        float val = rel_d[hd * 12 + di] + rel_w[hd * 12 + wi] + rel_h[hd * 12 + hi];
        short hh = f2bf(val);
        ph.s[o] = hh;
        pl.s[o] = f2bf(val - bf2f(hh));
    }
    size_t rowoff = ((size_t)bh * NVOX + n) * DE;
    *(uint4*)&QhiT[rowoff + DK + dd0] = ph.v;
    *(uint4*)&QloT[rowoff + DK + dd0] = pl.v;
}

// ---------------------------------------------------------------------------
// MFMA projection, K chunked 2x128.  grid (27, HEADS, B_), block 384.
// ---------------------------------------------------------------------------
struct FS {
    union {
        struct { short xhi[64 * XPITCH]; short xlo[64 * XPITCH]; } s;
        float cbuf[3][64][CPITCH];
    } u;
};

__global__ __launch_bounds__(384, 4)
void fproj_kernel(const short* __restrict__ xbhi, const short* __restrict__ xblo,
                  const short* __restrict__ whi, const short* __restrict__ wlo,
                  const float* __restrict__ bq, const float* __restrict__ bk,
                  const float* __restrict__ bv,
                  short* __restrict__ QhiT, short* __restrict__ QloT,
                  short* __restrict__ KhiT, short* __restrict__ KloT,
                  short* __restrict__ Vbf) {
    __shared__ FS sm;
    int nb = blockIdx.x * 64, h = blockIdx.y, b = blockIdx.z;
    int bh = b * HEADS + h;
    int t = threadIdx.x;
    int w = t >> 6, l = t & 63, ln = l & 31, hv = l >> 5;
    int mat = w >> 1, nh = w & 1;

    const short* xh = xbhi + ((size_t)b * NVOX + nb) * C_;
    const short* xl = xblo + ((size_t)b * NVOX + nb) * C_;
    const short* wAh = whi + ((size_t)mat * C_ + h * DK + ln) * C_;
    const short* wAl = wlo + ((size_t)mat * C_ + h * DK + ln) * C_;
    int xrow = (nh * 32 + ln) * XPITCH;

    f32x16 acc;
    #pragma unroll
    for (int r = 0; r < 16; r++) acc[r] = 0.f;

    #pragma unroll 1
    for (int ch = 0; ch < 2; ch++) {
        __syncthreads();   // previous chunk fully consumed
        for (int e = t; e < 1024; e += 384) {
            int row = e >> 4, c8 = (e & 15) * 8;
            *(uint4*)&sm.u.s.xhi[row * XPITCH + c8] =
                *(const uint4*)&xh[row * C_ + ch * 128 + c8];
            *(uint4*)&sm.u.s.xlo[row * XPITCH + c8] =
                *(const uint4*)&xl[row * C_ + ch * 128 + c8];
        }
        __syncthreads();
        #pragma unroll 4
        for (int ks = 0; ks < 8; ks++) {
            int kl_ = ks * 16 + hv * 8;
            int kg = ch * 128 + kl_;
            bf16x8 ah = *(const bf16x8*)&wAh[kg];
            bf16x8 al = *(const bf16x8*)&wAl[kg];
            bf16x8 bh = *(const bf16x8*)&sm.u.s.xhi[xrow + kl_];
            bf16x8 bl = *(const bf16x8*)&sm.u.s.xlo[xrow + kl_];
            acc = mfma32(ah, bh, acc);
            acc = mfma32(al, bh, acc);
            acc = mfma32(ah, bl, acc);
        }
    }
    __syncthreads();   // x tiles dead; reuse as cbuf

    const float* bias = (mat == 0) ? bq : (mat == 1) ? bk : bv;
    int ncol = nh * 32 + ln;
    #pragma unroll
    for (int q2 = 0; q2 < 4; q2++) {
        float4 cv;
        float* cvp = (float*)&cv;
        #pragma unroll
        for (int m = 0; m < 4; m++) {
            int o_loc = 8 * q2 + 4 * hv + m;
            cvp[m] = acc[4 * q2 + m] + bias[h * DK + o_loc];
        }
        *(float4*)&sm.u.cbuf[mat][ncol][8 * q2 + 4 * hv] = cv;
    }
    __syncthreads();

    // ---- readout q/k (hi/lo both) ----
    if (t < 256) {
        int n = t >> 2, ddg = (t & 3) * 8;
        size_t rowoff = ((size_t)bh * NVOX + nb + n) * DE;
        union { short s[8]; uint4 v; } qh, ql, kh, kl;
        #pragma unroll
        for (int j = 0; j < 8; j++) {
            float qv = sm.u.cbuf[0][n][ddg + j];
            short hh = f2bf(qv);
            qh.s[j] = hh;
            ql.s[j] = f2bf(qv - bf2f(hh));
            float kv = sm.u.cbuf[1][n][ddg + j];
            short kk = f2bf(kv);
            kh.s[j] = kk;
            kl.s[j] = f2bf(kv - bf2f(kk));
        }
        *(uint4*)&QhiT[rowoff + ddg] = qh.v;
        *(uint4*)&QloT[rowoff + ddg] = ql.v;
        *(uint4*)&KhiT[rowoff + ddg] = kh.v;
        *(uint4*)&KloT[rowoff + ddg] = kl.v;
        *(uint4*)&KhiT[rowoff + DK + ddg] = qh.v;   // K' upper = q
        *(uint4*)&KloT[rowoff + DK + ddg] = ql.v;
    }
    // ---- readout v ----
    if (t < 256) {
        int d = t >> 3, ng = (t & 7) * 8;
        union { short s[8]; uint4 v; } vv;
        #pragma unroll
        for (int j = 0; j < 8; j++)
            vv.s[j] = f2bf(sm.u.cbuf[2][ng + j][d]);
        *(uint4*)&Vbf[((size_t)bh * DK + d) * NVOX + nb + ng] = vv.v;
    }
}

// ---------------------------------------------------------------------------
// Flash attention partial: BARRIER-FREE.  K'/V fragments load directly from
// global (L1/L2 reuse across the 3 same-(bh,jp) waves of a block); LDS holds
// only the wave-private P round-trip (C-layout -> B-layout).
// grid (54, HEADS, B_): jp = bx%3, itg = bx/3; wave w -> i-slab itg*3+w.
// Block 192 = 3 waves x 32 i-rows.  LDS 13.8 KB, no __syncthreads.
// ---------------------------------------------------------------------------
__global__ __launch_bounds__(192, 4)
void attn_kernel(const short* __restrict__ QhiT, const short* __restrict__ QloT,
                 const short* __restrict__ KhiT, const short* __restrict__ KloT,
                 const short* __restrict__ Vbf,
                 short* __restrict__ wsO, float* __restrict__ wsM,
                 float* __restrict__ wsL) {
    __shared__ short P[3][32][PITCH];
    int bx = blockIdx.x;
    int jp = bx % 3, itg = bx / 3;
    int h = blockIdx.y, b = blockIdx.z;
    int bh = b * HEADS + h;
    int t = threadIdx.x;
    int w  = t >> 6;
    int l  = t & 63;
    int ln = l & 31;
    int hv = l >> 5;
    int i_glob = (itg * 3 + w) * 32 + ln;

    const short* Qh = QhiT + (size_t)bh * NVOX * DE;
    const short* Ql = QloT + (size_t)bh * NVOX * DE;
    const short* Kh = KhiT + (size_t)bh * NVOX * DE;
    const short* Kl = KloT + (size_t)bh * NVOX * DE;
    const short* Vp = Vbf  + (size_t)bh * DK * NVOX;

    bf16x8 qfh[4], qfl[4];
    #pragma unroll
    for (int ks = 0; ks < 4; ks++) {
        size_t off = (size_t)i_glob * DE + ks * 16 + hv * 8;
        qfh[ks] = *(const bf16x8*)&Qh[off];
        qfl[ks] = *(const bf16x8*)&Ql[off];
    }

    float mL = -INFINITY;
    float lsum = 0.f;
    f32x16 O;
    #pragma unroll
    for (int r = 0; r < 16; r++) O[r] = 0.f;

    int jt0 = jp * 9, jt1 = jt0 + 9;
    #pragma unroll 1
    for (int jt = jt0; jt < jt1; jt++) {
        int jb = jt * 64;

        // ---- S^T: fragments straight from global ----
        f32x16 sc[2];
        #pragma unroll
        for (int js = 0; js < 2; js++) {
            f32x16 s;
            #pragma unroll
            for (int r = 0; r < 16; r++) s[r] = 0.f;
            size_t krow = (size_t)(jb + js * 32 + ln) * DE + hv * 8;
            #pragma unroll
            for (int ks = 0; ks < 4; ks++) {
                bf16x8 kh = *(const bf16x8*)&Kh[krow + ks * 16];
                bf16x8 kl = *(const bf16x8*)&Kl[krow + ks * 16];
                s = mfma32(kh, qfh[ks], s);
                s = mfma32(kh, qfl[ks], s);
                s = mfma32(kl, qfh[ks], s);
            }
            sc[js] = s;
        }

        // ---- online softmax (i = ln per lane; 1 shuffle per reduction) ----
        float mx = sc[0][0];
        #pragma unroll
        for (int js = 0; js < 2; js++)
            #pragma unroll
            for (int r = 0; r < 16; r++) mx = fmaxf(mx, sc[js][r]);
        mx = fmaxf(mx, __shfl_xor(mx, 32));
        float mLn = fmaxf(mL, mx * LOG2E);
        float alpha = exp2f(mL - mLn);
        mL = mLn;
        float ps = 0.f;
        #pragma unroll
        for (int js = 0; js < 2; js++)
            #pragma unroll
            for (int r = 0; r < 16; r++) {
                float p = exp2f(fmaf(sc[js][r], LOG2E, -mLn));
                sc[js][r] = p;
                ps += p;
            }
        ps += __shfl_xor(ps, 32);
        lsum = lsum * alpha + ps;

        // ---- P: C-layout -> LDS [i][j] (wave-private; no barrier) ----
        #pragma unroll
        for (int js = 0; js < 2; js++)
            #pragma unroll
            for (int g = 0; g < 4; g++) {
                unsigned u0 = __float_as_uint(sc[js][4 * g + 0]) + 0x8000u;
                unsigned u1 = __float_as_uint(sc[js][4 * g + 1]) + 0x8000u;
                unsigned u2 = __float_as_uint(sc[js][4 * g + 2]) + 0x8000u;
                unsigned u3 = __float_as_uint(sc[js][4 * g + 3]) + 0x8000u;
                uint2 pk;
                pk.x = __builtin_amdgcn_perm(u1, u0, 0x07060302);
                pk.y = __builtin_amdgcn_perm(u3, u2, 0x07060302);
                *(uint2*)&P[w][ln][js * 32 + g * 8 + hv * 4] = pk;
            }

        // ---- O^T += Vt * P  (V-frags from global, P-frags from LDS) ----
        #pragma unroll
        for (int r = 0; r < 16; r++) O[r] *= alpha;
        #pragma unroll
        for (int ks = 0; ks < 4; ks++) {
            bf16x8 va = *(const bf16x8*)&Vp[(size_t)ln * NVOX + jb + ks * 16 + hv * 8];
            bf16x8 pb = *(const bf16x8*)&P[w][ln][ks * 16 + hv * 8];
            O = mfma32(va, pb, O);
        }
    }

    // ---- partial epilogue: bf16 unnormalized O^T + (m, l) ----
    short* Op = wsO + ((size_t)jp * (B_ * HEADS) + bh) * DK * NVOX;
    #pragma unroll
    for (int r = 0; r < 16; r++) {
        int d = (r & 3) + 8 * (r >> 2) + 4 * hv;
        Op[(size_t)d * NVOX + i_glob] = f2bf(O[r]);
    }
    if (hv == 0) {
        size_t mo = ((size_t)jp * (B_ * HEADS) + bh) * NVOX + i_glob;
        wsM[mo] = mL;
        wsL[mo] = lsum;
    }
}

// ---------------------------------------------------------------------------
// Combine the three j-third partials (flash merge identity), bf16 partials.
// ---------------------------------------------------------------------------
__global__ void combine_kernel(const short* __restrict__ wsO,
                               const float* __restrict__ wsM,
                               const float* __restrict__ wsL,
                               float* __restrict__ out) {
    int idx = blockIdx.x * 256 + threadIdx.x;   // 1,769,472
    int i = idx % NVOX;
    int bh = (idx / NVOX) >> 5;
    const size_t oh = (size_t)B_ * HEADS * DK * NVOX;
    const size_t mh = (size_t)B_ * HEADS * NVOX;
    size_t mo = (size_t)bh * NVOX + i;
    float m0 = wsM[mo], m1 = wsM[mh + mo], m2 = wsM[2 * mh + mo];
    float m = fmaxf(fmaxf(m0, m1), m2);
    float a0 = exp2f(m0 - m), a1 = exp2f(m1 - m), a2 = exp2f(m2 - m);
    float num = a0 * bf2f(wsO[idx]) + a1 * bf2f(wsO[oh + idx]) + a2 * bf2f(wsO[2 * oh + idx]);
    float den = a0 * wsL[mo] + a1 * wsL[mh + mo] + a2 * wsL[2 * mh + mo];
    out[idx] = num / den;
}

// ---------------------------------------------------------------------------
extern "C" void kernel_launch(void* const* d_in, const int* in_sizes, int n_in,
                              void* d_out, int out_size, void* d_ws, size_t ws_size,
                              hipStream_t stream) {
    const float* x     = (const float*)d_in[0];
    const float* wq    = (const float*)d_in[1];
    const float* bq    = (const float*)d_in[2];
    const float* wk    = (const float*)d_in[3];
    const float* bk    = (const float*)d_in[4];
    const float* wv    = (const float*)d_in[5];
    const float* bv    = (const float*)d_in[6];
    const float* rel_d = (const float*)d_in[7];
    const float* rel_h = (const float*)d_in[8];
    const float* rel_w = (const float*)d_in[9];
    float* out = (float*)d_out;

    size_t qksz = (size_t)B_ * HEADS * NVOX * DE;        // 3,538,944 shorts
    size_t vsz  = (size_t)B_ * HEADS * DK * NVOX;        // 1,769,472
    short* QhiT = (short*)d_ws;
    short* QloT = QhiT + qksz;
    short* KhiT = QloT + qksz;
    short* KloT = KhiT + qksz;
    short* Vbf  = KloT + qksz;
    short* whi  = Vbf + vsz;                             // 196,608 shorts
    short* wlo  = whi + (size_t)3 * C_ * C_;
    short* wsO  = wlo + (size_t)3 * C_ * C_;             // 3*vsz shorts (bf16)
    float* wsM  = (float*)(wsO + 3 * vsz);               // 3*B*H*NVOX floats
    float* wsL  = wsM + 3 * (size_t)B_ * HEADS * NVOX;
    // xbhi/xblo alias the wsO region (dead before attn writes it)
    short* xbhi = wsO;
    short* xblo = xbhi + (size_t)B_ * NVOX * C_;         // 1,769,472 shorts each

    wsplit_kernel<<<dim3(3 * C_ * C_ / 256), dim3(256), 0, stream>>>(wq, wk, wv, whi, wlo);
    xsplit_kernel<<<dim3(NVOX / 64, C_ / 64, B_), dim3(256), 0, stream>>>(x, xbhi, xblo);
    pos_kernel<<<dim3(NVOX / 64, HEADS, B_), dim3(256), 0, stream>>>(
        rel_d, rel_h, rel_w, QhiT, QloT);
    fproj_kernel<<<dim3(NVOX / 64, HEADS, B_), dim3(384), 0, stream>>>(
        xbhi, xblo, whi, wlo, bq, bk, bv, QhiT, QloT, KhiT, KloT, Vbf);
    attn_kernel<<<dim3(3 * NVOX / 96, HEADS, B_), dim3(192), 0, stream>>>(
        QhiT, QloT, KhiT, KloT, Vbf, wsO, wsM, wsL);
    combine_kernel<<<dim3((int)(vsz / 256)), dim3(256), 0, stream>>>(wsO, wsM, wsL, out);
}

// Round 8
// 165.049 us; speedup vs baseline: 1.5497x; 1.5497x over previous
//
#include <hip/hip_runtime.h>
#include <math.h>

#define HEADS 8
#define DK 32
#define B_ 4
#define C_ 256
#define NVOX 1728   // 12*12*12
#define DE 64       // effective head dim: Q'=[q;pos], K'=[k;q]
#define PITCH 72    // attn LDS pitch (shorts): 144 B rows (row stride = 4 banks)
#define XPITCH 136  // fproj x-chunk LDS pitch (shorts): 272 B
#define CPITCH 36   // fproj cbuf pitch (floats)
#define LOG2E 1.44269504088896f

typedef _Float16 f16x8 __attribute__((ext_vector_type(8)));
typedef float f32x16 __attribute__((ext_vector_type(16)));

__device__ inline float h2f(short s) {
    _Float16 h = *(_Float16*)&s;
    return (float)h;
}
__device__ inline f32x16 mfma32h(f16x8 a, f16x8 b, f32x16 c) {
    return __builtin_amdgcn_mfma_f32_32x32x16_f16(a, b, c, 0, 0, 0);
}

union H8 { _Float16 h[8]; uint4 v; };
union H4 { _Float16 h[4]; uint2 v; };

// ---------------------------------------------------------------------------
// Weights -> f16 (layout [mat][o][c])
// ---------------------------------------------------------------------------
__global__ void wf16_kernel(const float* __restrict__ wq,
                            const float* __restrict__ wk,
                            const float* __restrict__ wv,
                            short* __restrict__ wf) {
    int idx = blockIdx.x * 256 + threadIdx.x;   // 3*65536
    int m = idx >> 16;
    const float* w = (m == 0) ? wq : (m == 1) ? wk : wv;
    _Float16 h = (_Float16)w[idx & 65535];
    wf[idx] = *(short*)&h;
}

// ---------------------------------------------------------------------------
// x transpose -> f16:  x[b][c][n] fp32 -> xf [b][n][c] f16
// ---------------------------------------------------------------------------
__global__ __launch_bounds__(256)
void xf16_kernel(const float* __restrict__ x, short* __restrict__ xf) {
    __shared__ float tile[64][65];
    int nb = blockIdx.x * 64, c0 = blockIdx.y * 64, b = blockIdx.z;
    int t = threadIdx.x;
    const float* xb = x + (size_t)b * C_ * NVOX;
    for (int e = t; e < 4096; e += 256) {
        int ci = e >> 6, nl = e & 63;
        tile[ci][nl] = xb[(size_t)(c0 + ci) * NVOX + nb + nl];
    }
    __syncthreads();
    for (int e = t; e < 512; e += 256) {
        int n = e >> 3, cg = (e & 7) * 8;
        H8 hi;
        #pragma unroll
        for (int j = 0; j < 8; j++) hi.h[j] = (_Float16)tile[cg + j][n];
        size_t off = ((size_t)b * NVOX + nb + n) * C_ + c0 + cg;
        *(uint4*)&xf[off] = hi.v;
    }
}

// ---------------------------------------------------------------------------
// pos -> Q' upper half [32:64), f16.  grid (27, HEADS, B_), block 256.
// ---------------------------------------------------------------------------
__global__ void pos_kernel(const float* __restrict__ rel_d,
                           const float* __restrict__ rel_h,
                           const float* __restrict__ rel_w,
                           short* __restrict__ Qf) {
    int t = threadIdx.x;
    int nl = t & 63, dd0 = (t >> 6) * 8;
    int n = blockIdx.x * 64 + nl;
    int h = blockIdx.y, b = blockIdx.z;
    int bh = b * HEADS + h;
    int di = n / 144, wi = (n / 12) % 12, hi = n % 12;
    H8 ph;
    #pragma unroll
    for (int o = 0; o < 8; o++) {
        int hd = h * DK + dd0 + o;
        ph.h[o] = (_Float16)(rel_d[hd * 12 + di] + rel_w[hd * 12 + wi] + rel_h[hd * 12 + hi]);
    }
    *(uint4*)&Qf[((size_t)bh * NVOX + n) * DE + DK + dd0] = ph.v;
}

// ---------------------------------------------------------------------------
// MFMA projection (f16 single), K chunked 2x128.
// grid (27, HEADS, B_), block 384 = 6 waves = 3 mats x 2 n-halves.
// ---------------------------------------------------------------------------
struct FS {
    union {
        short xs[64 * XPITCH];
        float cbuf[3][64][CPITCH];
    } u;
};

__global__ __launch_bounds__(384, 4)
void fproj_kernel(const short* __restrict__ xf, const short* __restrict__ wf,
                  const float* __restrict__ bq, const float* __restrict__ bk,
                  const float* __restrict__ bv,
                  short* __restrict__ Qf, short* __restrict__ Kf,
                  short* __restrict__ Vf) {
    __shared__ FS sm;
    int nb = blockIdx.x * 64, h = blockIdx.y, b = blockIdx.z;
    int bh = b * HEADS + h;
    int t = threadIdx.x;
    int w = t >> 6, l = t & 63, ln = l & 31, hv = l >> 5;
    int mat = w >> 1, nh = w & 1;

    const short* xb = xf + ((size_t)b * NVOX + nb) * C_;
    const short* wA = wf + ((size_t)mat * C_ + h * DK + ln) * C_;
    int xrow = (nh * 32 + ln) * XPITCH;

    f32x16 acc;
    #pragma unroll
    for (int r = 0; r < 16; r++) acc[r] = 0.f;

    #pragma unroll 1
    for (int ch = 0; ch < 2; ch++) {
        __syncthreads();
        for (int e = t; e < 1024; e += 384) {
            int row = e >> 4, c8 = (e & 15) * 8;
            *(uint4*)&sm.u.xs[row * XPITCH + c8] =
                *(const uint4*)&xb[row * C_ + ch * 128 + c8];
        }
        __syncthreads();
        #pragma unroll 4
        for (int ks = 0; ks < 8; ks++) {
            int kl_ = ks * 16 + hv * 8;
            f16x8 a = *(const f16x8*)&wA[ch * 128 + kl_];
            f16x8 bfr = *(const f16x8*)&sm.u.xs[xrow + kl_];
            acc = mfma32h(a, bfr, acc);
        }
    }
    __syncthreads();   // x tile dead; reuse as cbuf

    const float* bias = (mat == 0) ? bq : (mat == 1) ? bk : bv;
    int ncol = nh * 32 + ln;
    #pragma unroll
    for (int q2 = 0; q2 < 4; q2++) {
        float4 cv;
        float* cvp = (float*)&cv;
        #pragma unroll
        for (int m = 0; m < 4; m++) {
            int o_loc = 8 * q2 + 4 * hv + m;
            cvp[m] = acc[4 * q2 + m] + bias[h * DK + o_loc];
        }
        *(float4*)&sm.u.cbuf[mat][ncol][8 * q2 + 4 * hv] = cv;
    }
    __syncthreads();

    // ---- readout q/k ----
    if (t < 256) {
        int n = t >> 2, ddg = (t & 3) * 8;
        size_t rowoff = ((size_t)bh * NVOX + nb + n) * DE;
        H8 qh, kh;
        #pragma unroll
        for (int j = 0; j < 8; j++) {
            qh.h[j] = (_Float16)sm.u.cbuf[0][n][ddg + j];
            kh.h[j] = (_Float16)sm.u.cbuf[1][n][ddg + j];
        }
        *(uint4*)&Qf[rowoff + ddg] = qh.v;
        *(uint4*)&Kf[rowoff + ddg] = kh.v;
        *(uint4*)&Kf[rowoff + DK + ddg] = qh.v;   // K' upper = q
    }
    // ---- readout v ----
    if (t < 256) {
        int d = t >> 3, ng = (t & 7) * 8;
        H8 vv;
        #pragma unroll
        for (int j = 0; j < 8; j++)
            vv.h[j] = (_Float16)sm.u.cbuf[2][ng + j][d];
        *(uint4*)&Vf[((size_t)bh * DK + d) * NVOX + nb + ng] = vv.v;
    }
}

// ---------------------------------------------------------------------------
// Flash attention partial: 32x32x16 f16 MFMA, S^T orientation, LDS-staged
// K'/V, j-split in 3.  grid (54, HEADS, B_), block 192.  LDS 27.6 KB.
// ---------------------------------------------------------------------------
struct SMem {
    short K[64][PITCH];
    short V[DK][PITCH];
    short P[96][PITCH];
};

__global__ __launch_bounds__(192, 4)
void attn_kernel(const short* __restrict__ Qf, const short* __restrict__ Kf,
                 const short* __restrict__ Vf,
                 short* __restrict__ wsO, float* __restrict__ wsM,
                 float* __restrict__ wsL) {
    __shared__ SMem sm;
    int bx = blockIdx.x;
    int it = bx / 3, jp = bx % 3;
    int h = blockIdx.y, b = blockIdx.z;
    int bh = b * HEADS + h;
    int t = threadIdx.x;
    int w  = t >> 6;
    int l  = t & 63;
    int ln = l & 31;
    int hv = l >> 5;
    int i_loc  = w * 32 + ln;
    int i_glob = it * 96 + i_loc;

    const short* Qp = Qf + (size_t)bh * NVOX * DE;
    const short* Kp = Kf + (size_t)bh * NVOX * DE;
    const short* Vp = Vf + (size_t)bh * DK * NVOX;

    f16x8 qf[4];
    #pragma unroll
    for (int ks = 0; ks < 4; ks++)
        qf[ks] = *(const f16x8*)&Qp[(size_t)i_glob * DE + ks * 16 + hv * 8];

    float mL = -INFINITY;
    float lsum = 0.f;
    f32x16 O;
    #pragma unroll
    for (int r = 0; r < 16; r++) O[r] = 0.f;

    int jt0 = jp * 9, jt1 = jt0 + 9;
    #pragma unroll 1
    for (int jt = jt0; jt < jt1; jt++) {
        int jb = jt * 64;
        __syncthreads();
        for (int e = t; e < 512; e += 192) {
            int row = e >> 3, c = (e & 7) * 8;
            *(uint4*)&sm.K[row][c] = *(const uint4*)&Kp[(size_t)(jb + row) * DE + c];
        }
        for (int e = t; e < 256; e += 192) {
            int d = e >> 3, c = (e & 7) * 8;
            *(uint4*)&sm.V[d][c] = *(const uint4*)&Vp[(size_t)d * NVOX + jb + c];
        }
        __syncthreads();

        // ---- S^T: two 32x32 j-subtiles, single f16 MFMA per k-step ----
        f32x16 sc[2];
        #pragma unroll
        for (int js = 0; js < 2; js++) {
            f32x16 s;
            #pragma unroll
            for (int r = 0; r < 16; r++) s[r] = 0.f;
            #pragma unroll
            for (int ks = 0; ks < 4; ks++) {
                f16x8 kfr = *(const f16x8*)&sm.K[js * 32 + ln][ks * 16 + hv * 8];
                s = mfma32h(kfr, qf[ks], s);
            }
            sc[js] = s;
        }

        // ---- online softmax (i = ln per lane; 1 shuffle per reduction) ----
        float mx = sc[0][0];
        #pragma unroll
        for (int js = 0; js < 2; js++)
            #pragma unroll
            for (int r = 0; r < 16; r++) mx = fmaxf(mx, sc[js][r]);
        mx = fmaxf(mx, __shfl_xor(mx, 32));
        float mLn = fmaxf(mL, mx * LOG2E);
        float alpha = exp2f(mL - mLn);
        mL = mLn;
        float ps = 0.f;
        #pragma unroll
        for (int js = 0; js < 2; js++)
            #pragma unroll
            for (int r = 0; r < 16; r++) {
                float p = exp2f(fmaf(sc[js][r], LOG2E, -mLn));
                sc[js][r] = p;
                ps += p;
            }
        ps += __shfl_xor(ps, 32);
        lsum = lsum * alpha + ps;

        // ---- P: C-layout -> LDS [i][j] f16 (reg group g = 4 consecutive j) --
        #pragma unroll
        for (int js = 0; js < 2; js++)
            #pragma unroll
            for (int g = 0; g < 4; g++) {
                H4 pk;
                #pragma unroll
                for (int m = 0; m < 4; m++) pk.h[m] = (_Float16)sc[js][4 * g + m];
                *(uint2*)&sm.P[i_loc][js * 32 + g * 8 + hv * 4] = pk.v;
            }

        // ---- O^T += Vt * P ----
        #pragma unroll
        for (int r = 0; r < 16; r++) O[r] *= alpha;
        #pragma unroll
        for (int ks = 0; ks < 4; ks++) {
            f16x8 va = *(const f16x8*)&sm.V[ln][ks * 16 + hv * 8];
            f16x8 pb = *(const f16x8*)&sm.P[i_loc][ks * 16 + hv * 8];
            O = mfma32h(va, pb, O);
        }
    }

    // ---- partial epilogue: f16 unnormalized O^T + (m, l) ----
    short* Op = wsO + ((size_t)jp * (B_ * HEADS) + bh) * DK * NVOX;
    #pragma unroll
    for (int r = 0; r < 16; r++) {
        int d = (r & 3) + 8 * (r >> 2) + 4 * hv;
        _Float16 oh = (_Float16)O[r];
        Op[(size_t)d * NVOX + i_glob] = *(short*)&oh;
    }
    if (hv == 0) {
        size_t mo = ((size_t)jp * (B_ * HEADS) + bh) * NVOX + i_glob;
        wsM[mo] = mL;
        wsL[mo] = lsum;
    }
}

// ---------------------------------------------------------------------------
// Combine the three j-third partials (flash merge identity), f16 partials.
// ---------------------------------------------------------------------------
__global__ void combine_kernel(const short* __restrict__ wsO,
                               const float* __restrict__ wsM,
                               const float* __restrict__ wsL,
                               float* __restrict__ out) {
    int idx = blockIdx.x * 256 + threadIdx.x;   // 1,769,472
    int i = idx % NVOX;
    int bh = (idx / NVOX) >> 5;
    const size_t oh = (size_t)B_ * HEADS * DK * NVOX;
    const size_t mh = (size_t)B_ * HEADS * NVOX;
    size_t mo = (size_t)bh * NVOX + i;
    float m0 = wsM[mo], m1 = wsM[mh + mo], m2 = wsM[2 * mh + mo];
    float m = fmaxf(fmaxf(m0, m1), m2);
    float a0 = exp2f(m0 - m), a1 = exp2f(m1 - m), a2 = exp2f(m2 - m);
    float num = a0 * h2f(wsO[idx]) + a1 * h2f(wsO[oh + idx]) + a2 * h2f(wsO[2 * oh + idx]);
    float den = a0 * wsL[mo] + a1 * wsL[mh + mo] + a2 * wsL[2 * mh + mo];
    out[idx] = num / den;
}

// ---------------------------------------------------------------------------
extern "C" void kernel_launch(void* const* d_in, const int* in_sizes, int n_in,
                              void* d_out, int out_size, void* d_ws, size_t ws_size,
                              hipStream_t stream) {
    const float* x     = (const float*)d_in[0];
    const float* wq    = (const float*)d_in[1];
    const float* bq    = (const float*)d_in[2];
    const float* wk    = (const float*)d_in[3];
    const float* bk    = (const float*)d_in[4];
    const float* wv    = (const float*)d_in[5];
    const float* bv    = (const float*)d_in[6];
    const float* rel_d = (const float*)d_in[7];
    const float* rel_h = (const float*)d_in[8];
    const float* rel_w = (const float*)d_in[9];
    float* out = (float*)d_out;

    size_t qksz = (size_t)B_ * HEADS * NVOX * DE;        // 3,538,944
    size_t vsz  = (size_t)B_ * HEADS * DK * NVOX;        // 1,769,472
    short* Qf  = (short*)d_ws;
    short* Kf  = Qf + qksz;
    short* Vf  = Kf + qksz;
    short* wf  = Vf + vsz;                               // 196,608 shorts
    short* wsO = wf + (size_t)3 * C_ * C_;               // 3*vsz shorts (f16)
    float* wsM = (float*)(wsO + 3 * vsz);                // 3*B*H*NVOX floats
    float* wsL = wsM + 3 * (size_t)B_ * HEADS * NVOX;
    // xf aliases the wsO region (dead before attn writes it)
    short* xf  = wsO;                                    // B*NVOX*C_ shorts

    wf16_kernel<<<dim3(3 * C_ * C_ / 256), dim3(256), 0, stream>>>(wq, wk, wv, wf);
    xf16_kernel<<<dim3(NVOX / 64, C_ / 64, B_), dim3(256), 0, stream>>>(x, xf);
    pos_kernel<<<dim3(NVOX / 64, HEADS, B_), dim3(256), 0, stream>>>(
        rel_d, rel_h, rel_w, Qf);
    fproj_kernel<<<dim3(NVOX / 64, HEADS, B_), dim3(384), 0, stream>>>(
        xf, wf, bq, bk, bv, Qf, Kf, Vf);
    attn_kernel<<<dim3(3 * NVOX / 96, HEADS, B_), dim3(192), 0, stream>>>(
        Qf, Kf, Vf, wsO, wsM, wsL);
    combine_kernel<<<dim3((int)(vsz / 256)), dim3(256), 0, stream>>>(wsO, wsM, wsL, out);
}

// Round 10
// 159.022 us; speedup vs baseline: 1.6085x; 1.0379x over previous
//
#include <hip/hip_runtime.h>
#include <math.h>

#define HEADS 8
#define DK 32
#define B_ 4
#define C_ 256
#define NVOX 1728   // 12*12*12
#define DE 64       // effective head dim: Q'=[q;pos], K'=[k;q]
#define PITCH 72    // attn LDS pitch (shorts): 144 B rows
#define XPITCH 136  // fproj x-chunk LDS pitch (shorts)
#define CPITCH 36   // fproj cbuf pitch (floats)
#define LOG2E 1.44269504088896f

typedef _Float16 f16x8 __attribute__((ext_vector_type(8)));
typedef __fp16 fp16x2 __attribute__((ext_vector_type(2)));
typedef float f32x16 __attribute__((ext_vector_type(16)));

__device__ inline float h2f(short s) {
    _Float16 h = *(_Float16*)&s;
    return (float)h;
}
__device__ inline f32x16 mfma32h(f16x8 a, f16x8 b, f32x16 c) {
    return __builtin_amdgcn_mfma_f32_32x32x16_f16(a, b, c, 0, 0, 0);
}

union H8 { _Float16 h[8]; uint4 v; };

// ---------------------------------------------------------------------------
// Fused prep: [0,768) w->f16 | [768,1200) x transpose->f16 | [1200,2064) pos
// ---------------------------------------------------------------------------
__global__ __launch_bounds__(256)
void prep_kernel(const float* __restrict__ x,
                 const float* __restrict__ wq, const float* __restrict__ wk,
                 const float* __restrict__ wv,
                 const float* __restrict__ rel_d, const float* __restrict__ rel_h,
                 const float* __restrict__ rel_w,
                 short* __restrict__ wf, short* __restrict__ xf,
                 short* __restrict__ Qf) {
    __shared__ float tile[64][65];
    int bid = blockIdx.x;
    int t = threadIdx.x;

    if (bid < 768) {                       // ---- weights -> f16 ----
        int idx = bid * 256 + t;           // 3*65536 total
        int m = idx >> 16;
        const float* w = (m == 0) ? wq : (m == 1) ? wk : wv;
        _Float16 h = (_Float16)w[idx & 65535];
        wf[idx] = *(short*)&h;
    } else if (bid < 1200) {               // ---- x[b][c][n] -> xf[b][n][c] ----
        int q = bid - 768;                 // 432 blocks: (27, 4, 4)
        int nb = (q % 27) * 64;
        int c0 = ((q / 27) % 4) * 64;
        int b  = q / 108;
        const float* xb = x + (size_t)b * C_ * NVOX;
        for (int e = t; e < 4096; e += 256) {
            int ci = e >> 6, nl = e & 63;
            tile[ci][nl] = xb[(size_t)(c0 + ci) * NVOX + nb + nl];
        }
        __syncthreads();
        for (int e = t; e < 512; e += 256) {
            int n = e >> 3, cg = (e & 7) * 8;
            H8 hi;
            #pragma unroll
            for (int j = 0; j < 8; j++) hi.h[j] = (_Float16)tile[cg + j][n];
            *(uint4*)&xf[((size_t)b * NVOX + nb + n) * C_ + c0 + cg] = hi.v;
        }
    } else {                               // ---- pos -> Q' upper half ----
        int q = bid - 1200;                // 864 blocks: (27, 8, 4)
        int nb = (q % 27) * 64;
        int h  = (q / 27) % 8;
        int b  = q / 216;
        int bh = b * HEADS + h;
        int nl = t & 63, dd0 = (t >> 6) * 8;
        int n = nb + nl;
        int di = n / 144, wi = (n / 12) % 12, hi = n % 12;
        H8 ph;
        #pragma unroll
        for (int o = 0; o < 8; o++) {
            int hd = h * DK + dd0 + o;
            ph.h[o] = (_Float16)(rel_d[hd * 12 + di] + rel_w[hd * 12 + wi] +
                                 rel_h[hd * 12 + hi]);
        }
        *(uint4*)&Qf[((size_t)bh * NVOX + n) * DE + DK + dd0] = ph.v;
    }
}

// ---------------------------------------------------------------------------
// MFMA projection (f16), K chunked 2x128.  grid (27, HEADS, B_), block 384.
// ---------------------------------------------------------------------------
struct FS {
    union {
        short xs[64 * XPITCH];
        float cbuf[3][64][CPITCH];
    } u;
};

__global__ __launch_bounds__(384, 4)
void fproj_kernel(const short* __restrict__ xf, const short* __restrict__ wf,
                  const float* __restrict__ bq, const float* __restrict__ bk,
                  const float* __restrict__ bv,
                  short* __restrict__ Qf, short* __restrict__ Kf,
                  short* __restrict__ Vf) {
    __shared__ FS sm;
    int nb = blockIdx.x * 64, h = blockIdx.y, b = blockIdx.z;
    int bh = b * HEADS + h;
    int t = threadIdx.x;
    int w = t >> 6, l = t & 63, ln = l & 31, hv = l >> 5;
    int mat = w >> 1, nh = w & 1;

    const short* xb = xf + ((size_t)b * NVOX + nb) * C_;
    const short* wA = wf + ((size_t)mat * C_ + h * DK + ln) * C_;
    int xrow = (nh * 32 + ln) * XPITCH;

    f32x16 acc;
    #pragma unroll
    for (int r = 0; r < 16; r++) acc[r] = 0.f;

    #pragma unroll 1
    for (int ch = 0; ch < 2; ch++) {
        __syncthreads();
        for (int e = t; e < 1024; e += 384) {
            int row = e >> 4, c8 = (e & 15) * 8;
            *(uint4*)&sm.u.xs[row * XPITCH + c8] =
                *(const uint4*)&xb[row * C_ + ch * 128 + c8];
        }
        __syncthreads();
        #pragma unroll 4
        for (int ks = 0; ks < 8; ks++) {
            int kl_ = ks * 16 + hv * 8;
            f16x8 a = *(const f16x8*)&wA[ch * 128 + kl_];
            f16x8 bfr = *(const f16x8*)&sm.u.xs[xrow + kl_];
            acc = mfma32h(a, bfr, acc);
        }
    }
    __syncthreads();   // x tile dead; reuse as cbuf

    const float* bias = (mat == 0) ? bq : (mat == 1) ? bk : bv;
    int ncol = nh * 32 + ln;
    #pragma unroll
    for (int q2 = 0; q2 < 4; q2++) {
        float4 cv;
        float* cvp = (float*)&cv;
        #pragma unroll
        for (int m = 0; m < 4; m++) {
            int o_loc = 8 * q2 + 4 * hv + m;
            cvp[m] = acc[4 * q2 + m] + bias[h * DK + o_loc];
        }
        *(float4*)&sm.u.cbuf[mat][ncol][8 * q2 + 4 * hv] = cv;
    }
    __syncthreads();

    if (t < 256) {                          // ---- readout q/k ----
        int n = t >> 2, ddg = (t & 3) * 8;
        size_t rowoff = ((size_t)bh * NVOX + nb + n) * DE;
        H8 qh, kh;
        #pragma unroll
        for (int j = 0; j < 8; j++) {
            qh.h[j] = (_Float16)sm.u.cbuf[0][n][ddg + j];
            kh.h[j] = (_Float16)sm.u.cbuf[1][n][ddg + j];
        }
        *(uint4*)&Qf[rowoff + ddg] = qh.v;
        *(uint4*)&Kf[rowoff + ddg] = kh.v;
        *(uint4*)&Kf[rowoff + DK + ddg] = qh.v;   // K' upper = q
    }
    if (t < 256) {                          // ---- readout v ----
        int d = t >> 3, ng = (t & 7) * 8;
        H8 vv;
        #pragma unroll
        for (int j = 0; j < 8; j++)
            vv.h[j] = (_Float16)sm.u.cbuf[2][ng + j][d];
        *(uint4*)&Vf[((size_t)bh * DK + d) * NVOX + nb + ng] = vv.v;
    }
}

// ---------------------------------------------------------------------------
// Flash attention partial: 32x32x16 f16 MFMA, S^T orientation, i-tile 64
// (2 waves), j-split 2.  grid (54, HEADS, B_), block 128.  LDS 23.0 KB ->
// 6 blocks/CU (12 waves).
// ---------------------------------------------------------------------------
struct SMem {
    short K[64][PITCH];
    short V[DK][PITCH];
    short P[64][PITCH];
};

__global__ __launch_bounds__(128, 3)
void attn_kernel(const short* __restrict__ Qf, const short* __restrict__ Kf,
                 const short* __restrict__ Vf,
                 short* __restrict__ wsO, float* __restrict__ wsM,
                 float* __restrict__ wsL) {
    __shared__ SMem sm;
    int bx = blockIdx.x;
    int it = bx >> 1, jp = bx & 1;
    int h = blockIdx.y, b = blockIdx.z;
    int bh = b * HEADS + h;
    int t = threadIdx.x;
    int w  = t >> 6;
    int l  = t & 63;
    int ln = l & 31;
    int hv = l >> 5;
    int i_loc  = w * 32 + ln;
    int i_glob = it * 64 + i_loc;

    const short* Qp = Qf + (size_t)bh * NVOX * DE;
    const short* Kp = Kf + (size_t)bh * NVOX * DE;
    const short* Vp = Vf + (size_t)bh * DK * NVOX;

    f16x8 qf[4];
    #pragma unroll
    for (int ks = 0; ks < 4; ks++)
        qf[ks] = *(const f16x8*)&Qp[(size_t)i_glob * DE + ks * 16 + hv * 8];

    float mL = -INFINITY;
    float lsum = 0.f;
    f32x16 O;
    #pragma unroll
    for (int r = 0; r < 16; r++) O[r] = 0.f;

    int jt0 = jp ? 14 : 0, jt1 = jp ? 27 : 14;
    #pragma unroll 1
    for (int jt = jt0; jt < jt1; jt++) {
        int jb = jt * 64;
        __syncthreads();
        for (int e = t; e < 512; e += 128) {
            int row = e >> 3, c = (e & 7) * 8;
            *(uint4*)&sm.K[row][c] = *(const uint4*)&Kp[(size_t)(jb + row) * DE + c];
        }
        for (int e = t; e < 256; e += 128) {
            int d = e >> 3, c = (e & 7) * 8;
            *(uint4*)&sm.V[d][c] = *(const uint4*)&Vp[(size_t)d * NVOX + jb + c];
        }
        __syncthreads();

        // ---- S^T: two 32x32 j-subtiles ----
        f32x16 sc[2];
        #pragma unroll
        for (int js = 0; js < 2; js++) {
            f32x16 s;
            #pragma unroll
            for (int r = 0; r < 16; r++) s[r] = 0.f;
            #pragma unroll
            for (int ks = 0; ks < 4; ks++) {
                f16x8 kfr = *(const f16x8*)&sm.K[js * 32 + ln][ks * 16 + hv * 8];
                s = mfma32h(kfr, qf[ks], s);
            }
            sc[js] = s;
        }

        // ---- online softmax ----
        float mx = sc[0][0];
        #pragma unroll
        for (int js = 0; js < 2; js++)
            #pragma unroll
            for (int r = 0; r < 16; r++) mx = fmaxf(mx, sc[js][r]);
        mx = fmaxf(mx, __shfl_xor(mx, 32));
        float mLn = fmaxf(mL, mx * LOG2E);
        float alpha = exp2f(mL - mLn);
        mL = mLn;
        float ps = 0.f;
        #pragma unroll
        for (int js = 0; js < 2; js++)
            #pragma unroll
            for (int r = 0; r < 16; r++) {
                float p = exp2f(fmaf(sc[js][r], LOG2E, -mLn));
                sc[js][r] = p;
                ps += p;
            }
        ps += __shfl_xor(ps, 32);
        lsum = lsum * alpha + ps;

        // ---- P: C-layout -> LDS [i][j] f16, packed cvt ----
        #pragma unroll
        for (int js = 0; js < 2; js++)
            #pragma unroll
            for (int g = 0; g < 4; g++) {
                union { fp16x2 h2[2]; uint2 v; } pk;
                pk.h2[0] = __builtin_amdgcn_cvt_pkrtz(sc[js][4 * g + 0], sc[js][4 * g + 1]);
                pk.h2[1] = __builtin_amdgcn_cvt_pkrtz(sc[js][4 * g + 2], sc[js][4 * g + 3]);
                *(uint2*)&sm.P[i_loc][js * 32 + g * 8 + hv * 4] = pk.v;
            }

        // ---- O^T += Vt * P ----
        #pragma unroll
        for (int r = 0; r < 16; r++) O[r] *= alpha;
        #pragma unroll
        for (int ks = 0; ks < 4; ks++) {
            f16x8 va = *(const f16x8*)&sm.V[ln][ks * 16 + hv * 8];
            f16x8 pb = *(const f16x8*)&sm.P[i_loc][ks * 16 + hv * 8];
            O = mfma32h(va, pb, O);
        }
    }

    // ---- partial epilogue: f16 unnormalized O^T + (m, l) ----
    short* Op = wsO + ((size_t)jp * (B_ * HEADS) + bh) * DK * NVOX;
    #pragma unroll
    for (int r = 0; r < 16; r++) {
        int d = (r & 3) + 8 * (r >> 2) + 4 * hv;
        _Float16 oh = (_Float16)O[r];
        Op[(size_t)d * NVOX + i_glob] = *(short*)&oh;
    }
    if (hv == 0) {
        size_t mo = ((size_t)jp * (B_ * HEADS) + bh) * NVOX + i_glob;
        wsM[mo] = mL;
        wsL[mo] = lsum;
    }
}

// ---------------------------------------------------------------------------
// Combine the two j-half partials (flash merge identity), f16 partials.
// ---------------------------------------------------------------------------
__global__ void combine_kernel(const short* __restrict__ wsO,
                               const float* __restrict__ wsM,
                               const float* __restrict__ wsL,
                               float* __restrict__ out) {
    int idx = blockIdx.x * 256 + threadIdx.x;   // 1,769,472
    int i = idx % NVOX;
    int bh = (idx / NVOX) >> 5;
    const size_t oh = (size_t)B_ * HEADS * DK * NVOX;
    const size_t mh = (size_t)B_ * HEADS * NVOX;
    size_t mo = (size_t)bh * NVOX + i;
    float m0 = wsM[mo], m1 = wsM[mh + mo];
    float l0 = wsL[mo], l1 = wsL[mh + mo];
    float m = fmaxf(m0, m1);
    float a0 = exp2f(m0 - m), a1 = exp2f(m1 - m);
    float num = a0 * h2f(wsO[idx]) + a1 * h2f(wsO[oh + idx]);
    float den = a0 * l0 + a1 * l1;
    out[idx] = num / den;
}

// ---------------------------------------------------------------------------
extern "C" void kernel_launch(void* const* d_in, const int* in_sizes, int n_in,
                              void* d_out, int out_size, void* d_ws, size_t ws_size,
                              hipStream_t stream) {
    const float* x     = (const float*)d_in[0];
    const float* wq    = (const float*)d_in[1];
    const float* bq    = (const float*)d_in[2];
    const float* wk    = (const float*)d_in[3];
    const float* bk    = (const float*)d_in[4];
    const float* wv    = (const float*)d_in[5];
    const float* bv    = (const float*)d_in[6];
    const float* rel_d = (const float*)d_in[7];
    const float* rel_h = (const float*)d_in[8];
    const float* rel_w = (const float*)d_in[9];
    float* out = (float*)d_out;

    size_t qksz = (size_t)B_ * HEADS * NVOX * DE;        // 3,538,944
    size_t vsz  = (size_t)B_ * HEADS * DK * NVOX;        // 1,769,472
    short* Qf  = (short*)d_ws;
    short* Kf  = Qf + qksz;
    short* Vf  = Kf + qksz;
    short* wf  = Vf + vsz;                               // 196,608 shorts
    short* wsO = wf + (size_t)3 * C_ * C_;               // 2*vsz shorts (f16)
    float* wsM = (float*)(wsO + 2 * vsz);                // 2*B*H*NVOX floats
    float* wsL = wsM + 2 * (size_t)B_ * HEADS * NVOX;
    short* xf  = wsO;                                    // aliases wsO (dead before attn)

    prep_kernel<<<dim3(2064), dim3(256), 0, stream>>>(
        x, wq, wk, wv, rel_d, rel_h, rel_w, wf, xf, Qf);
    fproj_kernel<<<dim3(NVOX / 64, HEADS, B_), dim3(384), 0, stream>>>(
        xf, wf, bq, bk, bv, Qf, Kf, Vf);
    attn_kernel<<<dim3(2 * NVOX / 64, HEADS, B_), dim3(128), 0, stream>>>(
        Qf, Kf, Vf, wsO, wsM, wsL);
    combine_kernel<<<dim3((int)(vsz / 256)), dim3(256), 0, stream>>>(wsO, wsM, wsL, out);
}